// Round 19
// baseline (1067.123 us; speedup 1.0000x reference)
//
#include <hip/hip_runtime.h>
#include <math.h>

// LDGCNN forward: 4 EdgeConv blocks (knn K=20) + 1x1 conv block + global max pool + 3 FC.
// B=8, N=2048. Feature buffer X: (B, N, XS) rows, columns [pts(3)|f1(64)|f2(64)|f3(64)|f4(128)].
//
// R17: EdgeConv linearized -> dense GEMM (k_hg) + cache-resident gather+max (k_edgemax).
// R19/R24: k_stage5 RB=32 + wave-uniform scalar X loads. R23: k_dist float4 B-frags.
// R25: k_select radix-select (set semantics). R26 dbuf REGRESSED (VGPR/occupancy rule).
// R28 (this round): k_select one-wave rewrite. Old: 128 thr, 13 __syncthreads across the
// 6-level descent (~320us aggregate, largest phase). New: 64 thr (wave-synchronous, no
// s_barrier): pass1 bound B (wave-max of lane minima; >=64 keys <= B); pass2 ballot-compact
// survivors (k<=B) into LDS sKeys[2048] (worst-case safe, no atomics, no big reg arrays —
// avoids the R7/R17 VGPR trap); descent over compacted survivors (~5 keys/lane/level) with
// early-exit: bucket count <=8 -> gather + rank-select (typ. 2 levels not 6); emission
// ballot-compacts keys <= T from sKeys. Exact same set semantics as lax.top_k.

constexpr int BB = 8;
constexpr int NN = 2048;
constexpr int KK = 20;
constexpr int CT = 323;
constexpr int XS = 324;
constexpr int X4S = XS / 4;   // 81 float4 per row
constexpr float NEGS = 0.2f;

__device__ __forceinline__ float lrelu(float v) { return v > 0.0f ? v : NEGS * v; }

__device__ __forceinline__ void atomicMaxF(float* addr, float v) {
    if (v >= 0.0f) atomicMax((int*)addr, __float_as_int(v));
    else           atomicMin((unsigned int*)addr, __float_as_uint(v));
}

__device__ __forceinline__ void fma4(float4& a, float x, const float4 w) {
    a.x = fmaf(x, w.x, a.x); a.y = fmaf(x, w.y, a.y);
    a.z = fmaf(x, w.z, a.z); a.w = fmaf(x, w.w, a.w);
}

// ---- fused prep: WT packs + W5T transpose + gfeat init + transpose/sq0 + X zero-fill -----
constexpr int WTOT = 19072;
__global__ void k_prep_all(const float* __restrict__ W1, const float* __restrict__ W2,
                           const float* __restrict__ W3, const float* __restrict__ W4,
                           const float* __restrict__ W5, const float* __restrict__ x,
                           float4* __restrict__ WT4, float* __restrict__ W5T,
                           float* __restrict__ gfeat, float* __restrict__ X,
                           float* __restrict__ sq) {
    int j = blockIdx.x * blockDim.x + threadIdx.x;
    if (j < WTOT) {
        int base, Cout, C;
        const float* W;
        if (j < 128)       { base = 0;    Cout = 64;  C = 3;   W = W1; }
        else if (j < 2304) { base = 128;  Cout = 64;  C = 67;  W = W2; }
        else if (j < 6528) { base = 2304; Cout = 64;  C = 131; W = W3; }
        else               { base = 6528; Cout = 128; C = 195; W = W4; }
        int W4w = Cout / 2;                 // 2*Cout/4 float4 groups per channel row
        int local = j - base;
        int c = local / W4w, og = local - c * W4w;
        float v[4];
#pragma unroll
        for (int q = 0; q < 4; ++q) {
            int o2 = 4 * og + q;
            if (c >= C) v[q] = 0.f;
            else if (o2 < Cout) v[q] = W[(size_t)o2 * 2 * C + c];
            else {
                int o = o2 - Cout;
                v[q] = W[(size_t)o * 2 * C + C + c] - W[(size_t)o * 2 * C + c];
            }
        }
        WT4[j] = make_float4(v[0], v[1], v[2], v[3]);
    } else if (j < WTOT + XS * 1024) {
        int t = j - WTOT;
        int c = t / 1024, o = t % 1024;
        W5T[t] = (c < CT) ? W5[(size_t)o * CT + c] : 0.f;   // row 323 zeroed
    } else if (j < WTOT + XS * 1024 + BB * 1024) {
        gfeat[j - WTOT - XS * 1024] = -INFINITY;
    } else if (j < WTOT + XS * 1024 + BB * 1024 + BB * NN) {
        int i = j - WTOT - XS * 1024 - BB * 1024;            // b*NN + n
        int b = i >> 11, n = i & 2047;
        const float* xb = x + (size_t)b * 3 * NN;
        float vx = xb[n], vy = xb[NN + n], vz = xb[2 * NN + n];
        float* row = X + (size_t)i * XS;
        row[0] = vx; row[1] = vy; row[2] = vz; row[3] = 0.f;
        sq[i] = vx * vx + vy * vy + vz * vz;
    } else if (j < WTOT + XS * 1024 + BB * 1024 + BB * NN + BB * NN * 80) {
        // zero-fill X feature columns (float4 indices 1..80 of each row; col 3 done above)
        int t = j - (WTOT + XS * 1024 + BB * 1024 + BB * NN);
        int row = t / 80, c4 = 1 + (t - 80 * row);
        ((float4*)X)[(size_t)row * X4S + c4] = make_float4(0.f, 0.f, 0.f, 0.f);
    }
}

// ---- dist[b][n][m] = max(sq_n + sq_m - 2*dot, 0) — SYMMETRIC: only tiles ti>=tj ----------
// 128x128 tile, 8x8 per thread. Thread owns cols {tx*4..+3, 64+tx*4..+3}; B fragment is
// 2 ds_read_b128. Off-diagonal: direct float4 writes + mirrored 4-pass LDS transpose.
constexpr int TM = 128;
__global__ __launch_bounds__(256) void k_dist(const float* __restrict__ X,
                                              const float* __restrict__ sq,
                                              float* __restrict__ dist, int C) {
    int b = blockIdx.z;
    int blk = blockIdx.x;                 // 0..135 -> (ti, tj), ti >= tj
    int ti = (int)((sqrtf(8.0f * blk + 1.0f) - 1.0f) * 0.5f);
    while ((ti + 1) * (ti + 2) / 2 <= blk) ++ti;
    while (ti * (ti + 1) / 2 > blk) --ti;
    int tj = blk - ti * (ti + 1) / 2;
    int m0 = ti * TM;                     // col tile
    int n0 = tj * TM;                     // row tile
    __shared__ float smem[4352];          // 17 KB: staging (16 KB) / transpose T[32][129]
    float* AsB = smem;                    // As[16][TM]
    float* BsB = smem + 2048;             // Bs[16][TM]
    int tid = threadIdx.x;
    int tx = tid & 15;        // cols: m0 + h*64 + tx*4 + jj  (j = 4h+jj)
    int ty = tid >> 4;        // rows: n0 + ty*8 + i
    float acc[8][8] = {};
    const float* Xb = X + (size_t)b * NN * XS;
    int sr = tid & 127;       // staging row
    int sc0 = (tid >> 7) * 8; // staging channel half (0 or 8)
    for (int c0 = 0; c0 < C; c0 += 16) {
        const float* arow = Xb + (size_t)(n0 + sr) * XS + c0 + sc0;
        const float* brow = Xb + (size_t)(m0 + sr) * XS + c0 + sc0;
        float4 a0 = *(const float4*)(arow);
        float4 a1 = *(const float4*)(arow + 4);
        float4 b0 = *(const float4*)(brow);
        float4 b1 = *(const float4*)(brow + 4);
        float av[8] = {a0.x, a0.y, a0.z, a0.w, a1.x, a1.y, a1.z, a1.w};
        float bv8[8] = {b0.x, b0.y, b0.z, b0.w, b1.x, b1.y, b1.z, b1.w};
#pragma unroll
        for (int i = 0; i < 8; ++i) {
            bool inr = (c0 + sc0 + i) < C;
            AsB[(sc0 + i) * TM + sr] = inr ? av[i] : 0.f;
            BsB[(sc0 + i) * TM + sr] = inr ? bv8[i] : 0.f;
        }
        __syncthreads();
#pragma unroll
        for (int cc = 0; cc < 16; ++cc) {
            float4 a0r = *(const float4*)&AsB[cc * TM + ty * 8];
            float4 a1r = *(const float4*)&AsB[cc * TM + ty * 8 + 4];
            float a[8] = {a0r.x, a0r.y, a0r.z, a0r.w, a1r.x, a1r.y, a1r.z, a1r.w};
            float4 b0r = *(const float4*)&BsB[cc * TM + tx * 4];
            float4 b1r = *(const float4*)&BsB[cc * TM + 64 + tx * 4];
            float bv[8] = {b0r.x, b0r.y, b0r.z, b0r.w, b1r.x, b1r.y, b1r.z, b1r.w};
#pragma unroll
            for (int i = 0; i < 8; ++i)
#pragma unroll
                for (int j = 0; j < 8; ++j)
                    acc[i][j] = fmaf(a[i], bv[j], acc[i][j]);
        }
        __syncthreads();
    }
    const float* sqb = sq + b * NN;
    float* db = dist + (size_t)b * NN * NN;
    float sm[8];
#pragma unroll
    for (int j = 0; j < 8; ++j) sm[j] = sqb[m0 + (j >> 2) * 64 + tx * 4 + (j & 3)];
#pragma unroll
    for (int i = 0; i < 8; ++i) {
        int n = n0 + ty * 8 + i;
        float sn = sqb[n];
#pragma unroll
        for (int j = 0; j < 8; ++j) {
            float d = fmaxf(sn + sm[j] - 2.f * acc[i][j], 0.f);
            acc[i][j] = d;                                   // keep for mirror
        }
        *(float4*)&db[(size_t)n * NN + m0 + tx * 4] =
            make_float4(acc[i][0], acc[i][1], acc[i][2], acc[i][3]);
        *(float4*)&db[(size_t)n * NN + m0 + 64 + tx * 4] =
            make_float4(acc[i][4], acc[i][5], acc[i][6], acc[i][7]);
    }
    if (ti != tj) {
        // mirrored tile: rows m0.., cols n0.. — 4 passes (h: col half, p2: 32-row group)
        float* T = smem;                  // [32][129]
        int r = tid >> 3;                 // 0..31
        int c0r = (tid & 7) * 16;         // 0..112
#pragma unroll
        for (int h = 0; h < 2; ++h) {
#pragma unroll
            for (int p2 = 0; p2 < 2; ++p2) {
                __syncthreads();          // protect staging/previous pass reads
                if ((tx >> 3) == p2) {    // tx in [8*p2, 8*p2+8): m_local in [32p2, 32p2+32)
#pragma unroll
                    for (int jj = 0; jj < 4; ++jj)
#pragma unroll
                        for (int i = 0; i < 8; ++i)
                            T[((tx & 7) * 4 + jj) * 129 + ty * 8 + i] = acc[i][h * 4 + jj];
                }
                __syncthreads();
                float v[16];
#pragma unroll
                for (int k = 0; k < 16; ++k) v[k] = T[r * 129 + c0r + k];
                float* dst = db + (size_t)(m0 + h * 64 + 32 * p2 + r) * NN + n0 + c0r;
#pragma unroll
                for (int k = 0; k < 4; ++k)
                    *(float4*)(dst + 4 * k) = make_float4(v[4 * k], v[4 * k + 1],
                                                          v[4 * k + 2], v[4 * k + 3]);
            }
        }
    }
}

// ---- top-K smallest per row (SET semantics; one wave, barrier-free) ----------------------
// key = (bits(d)<<11)|m (unique; ties -> lower m = lax.top_k). B = wave-max of per-lane
// min32 (>=64 keys <= B => T <= B). Survivors (k<=B) ballot-compacted to sKeys (worst case
// 2048, no overflow path needed). Radix descent over survivors; early-exit when the chosen
// bucket has <=8 keys (gather + rank-select). Emission ballot-compacts keys <= T.
__global__ __launch_bounds__(64) void k_select(const float* __restrict__ dist,
                                               int* __restrict__ idx) {
    int bn = blockIdx.x;   // b*NN + n
    int lane = threadIdx.x;
    const float* drow = dist + (size_t)bn * NN;
    int m0 = lane * 32;
    unsigned long long lanebelow = (1ull << lane) - 1ull;
    // pass 1: bound B
    unsigned long long mn = ~0ull;
#pragma unroll
    for (int i = 0; i < 8; ++i) {
        float4 v = *(const float4*)(drow + m0 + 4 * i);
        unsigned long long k0 = ((unsigned long long)__float_as_uint(v.x) << 11) | (unsigned)(m0 + 4 * i + 0);
        unsigned long long k1 = ((unsigned long long)__float_as_uint(v.y) << 11) | (unsigned)(m0 + 4 * i + 1);
        unsigned long long k2 = ((unsigned long long)__float_as_uint(v.z) << 11) | (unsigned)(m0 + 4 * i + 2);
        unsigned long long k3 = ((unsigned long long)__float_as_uint(v.w) << 11) | (unsigned)(m0 + 4 * i + 3);
        mn = k0 < mn ? k0 : mn; mn = k1 < mn ? k1 : mn;
        mn = k2 < mn ? k2 : mn; mn = k3 < mn ? k3 : mn;
    }
    unsigned long long B = mn;
#pragma unroll
    for (int s = 1; s < 64; s <<= 1) {
        unsigned long long o = (unsigned long long)__shfl_xor((long long)B, s, 64);
        B = o > B ? o : B;
    }
    __shared__ unsigned long long sKeys[2048];   // 16 KB: worst-case all survivors
    __shared__ unsigned long long sSmall[8];
    __shared__ int hist[256];
    // pass 2: ballot-compact survivors into sKeys (no atomics, minimal registers)
    int base = 0;
#pragma unroll
    for (int i = 0; i < 8; ++i) {
        float4 v = *(const float4*)(drow + m0 + 4 * i);
        unsigned long long kk[4];
        kk[0] = ((unsigned long long)__float_as_uint(v.x) << 11) | (unsigned)(m0 + 4 * i + 0);
        kk[1] = ((unsigned long long)__float_as_uint(v.y) << 11) | (unsigned)(m0 + 4 * i + 1);
        kk[2] = ((unsigned long long)__float_as_uint(v.z) << 11) | (unsigned)(m0 + 4 * i + 2);
        kk[3] = ((unsigned long long)__float_as_uint(v.w) << 11) | (unsigned)(m0 + 4 * i + 3);
#pragma unroll
        for (int q = 0; q < 4; ++q) {
            bool p = kk[q] <= B;
            unsigned long long bal = __ballot(p);
            if (p) {
                int off = __popcll(bal & lanebelow);
                sKeys[base + off] = kk[q];
            }
            base += __popcll(bal);
        }
    }
    int nS = base;                                // wave-uniform
    __builtin_amdgcn_wave_barrier();
    // radix descent (wave-synchronous; LDS ops from one wave are in-order)
    unsigned long long T = 0;
    int want = KK;
#pragma unroll 1
    for (int level = 0; level < 6; ++level) {
        int sh = 40 - 8 * level;
        hist[lane] = 0; hist[lane + 64] = 0; hist[lane + 128] = 0; hist[lane + 192] = 0;
        __builtin_amdgcn_wave_barrier();
        for (int j = lane; j < nS; j += 64) {
            unsigned long long k = sKeys[j];
            if ((k >> (sh + 8)) == (T >> (sh + 8)))
                atomicAdd(&hist[(int)((k >> sh) & 255)], 1);
        }
        __builtin_amdgcn_wave_barrier();
        int h0 = hist[4 * lane], h1 = hist[4 * lane + 1];
        int h2 = hist[4 * lane + 2], h3 = hist[4 * lane + 3];
        int s = h0 + h1 + h2 + h3;
        int inc = s;
#pragma unroll
        for (int d = 1; d < 64; d <<= 1) {
            int o = __shfl_up(inc, d, 64);
            if (lane >= d) inc += o;
        }
        int c = inc - s;                          // exclusive prefix
        int bsel = -1, rem = 0, bcnt = 0;
        if (c < want && want <= c + h0) { bsel = 4 * lane + 0; rem = want - c; bcnt = h0; } c += h0;
        if (bsel < 0 && c < want && want <= c + h1) { bsel = 4 * lane + 1; rem = want - c; bcnt = h1; } c += h1;
        if (bsel < 0 && c < want && want <= c + h2) { bsel = 4 * lane + 2; rem = want - c; bcnt = h2; } c += h2;
        if (bsel < 0 && c < want && want <= c + h3) { bsel = 4 * lane + 3; rem = want - c; bcnt = h3; }
        unsigned long long balv = __ballot(bsel >= 0);
        int src = (int)(__ffsll((unsigned long long)balv) - 1);
        unsigned long long Tn = T | ((unsigned long long)(bsel < 0 ? 0 : bsel) << sh);
        T    = (unsigned long long)__shfl((long long)Tn, src, 64);
        want = __shfl(rem, src, 64);
        bcnt = __shfl(bcnt, src, 64);
        if (bcnt <= 8) {                          // always true by level 5 (keys unique)
            // gather the bcnt keys with prefix (bits >= sh) into sSmall
            int gb = 0;
            int nSpad = (nS + 63) & ~63;
            for (int j = lane; j < nSpad; j += 64) {
                bool p = (j < nS) && ((sKeys[j] >> sh) == (T >> sh));
                unsigned long long bal2 = __ballot(p);
                if (p) {
                    int off = __popcll(bal2 & lanebelow);
                    sSmall[gb + off] = sKeys[j];
                }
                gb += __popcll(bal2);
            }
            __builtin_amdgcn_wave_barrier();
            // rank-select the want-th smallest of bcnt (unique) keys
            unsigned long long myk = (lane < bcnt) ? sSmall[lane] : ~0ull;
            int rank = 0;
#pragma unroll 1
            for (int j = 0; j < bcnt; ++j) rank += (sSmall[j] <= myk) ? 1 : 0;
            bool win = (lane < bcnt) && (rank == want);
            unsigned long long balw = __ballot(win);
            int srcw = (int)(__ffsll((unsigned long long)balw) - 1);
            T = (unsigned long long)__shfl((long long)myk, srcw, 64);
            break;
        }
    }
    // emission: exactly KK keys <= T, ballot-compacted from sKeys
    int* orow = idx + (size_t)bn * KK;
    int eb = 0;
    int nSpad = (nS + 63) & ~63;
    for (int j = lane; j < nSpad; j += 64) {
        bool p = (j < nS) && (sKeys[j] <= T);
        unsigned long long bal3 = __ballot(p);
        if (p) {
            int off = __popcll(bal3 & lanebelow);
            orow[eb + off] = (int)(sKeys[j] & 2047u);
        }
        eb += __popcll(bal3);
    }
}

// ---- k_hg: H = X.Wa^T, G = X.Wd^T — dense GEMM, no gather. -------------------------------
template <int KC4, int COUT>
__global__ __launch_bounds__(256)
void k_hg(const float* __restrict__ X, const float4* __restrict__ WT4,
          float* __restrict__ H, float* __restrict__ G) {
    constexpr int W4 = COUT / 2;            // 2*COUT/4 float4 outputs per channel row
    constexpr int RB2 = 32;
    constexpr int RPT = RB2 * W4 / 256;     // rows per thread (8 for COUT=128, 4 for 64)
    int bn0 = blockIdx.x * RB2;
    __shared__ float4 xs[RB2][KC4];
    int tid = threadIdx.x;
    const float4* X4 = (const float4*)X;
    for (int j = tid; j < RB2 * KC4; j += 256) {
        int r = j / KC4, c = j - r * KC4;
        xs[r][c] = X4[(size_t)(bn0 + r) * X4S + c];
    }
    __syncthreads();
    int og = tid & (W4 - 1);
    int rg = tid / W4;                      // row group
    float4 acc[RPT];
#pragma unroll
    for (int i = 0; i < RPT; ++i) acc[i] = make_float4(0.f, 0.f, 0.f, 0.f);
#pragma unroll 2
    for (int c4 = 0; c4 < KC4; ++c4) {
        float4 w0 = WT4[(size_t)(4 * c4 + 0) * W4 + og];
        float4 w1 = WT4[(size_t)(4 * c4 + 1) * W4 + og];
        float4 w2 = WT4[(size_t)(4 * c4 + 2) * W4 + og];
        float4 w3 = WT4[(size_t)(4 * c4 + 3) * W4 + og];
#pragma unroll
        for (int i = 0; i < RPT; ++i) {
            float4 xv = xs[rg * RPT + i][c4];
            fma4(acc[i], xv.x, w0);
            fma4(acc[i], xv.y, w1);
            fma4(acc[i], xv.z, w2);
            fma4(acc[i], xv.w, w3);
        }
    }
    int o2 = 4 * og;
#pragma unroll
    for (int i = 0; i < RPT; ++i) {
        int bn = bn0 + rg * RPT + i;
        if (o2 < COUT) *(float4*)&H[(size_t)bn * COUT + o2] = acc[i];
        else           *(float4*)&G[(size_t)bn * COUT + (o2 - COUT)] = acc[i];
    }
}

// ---- k_edgemax: X[bn, outoff+o] = max_k lrelu((H[idx[bn,k],o] + G[bn,o])*s+b) ------------
template <int COUT>
__global__ __launch_bounds__(256)
void k_edgemax(const float* __restrict__ H, const float* __restrict__ G,
               const int* __restrict__ idx, const float* __restrict__ scale,
               const float* __restrict__ bias, int outoff,
               float* __restrict__ X, float* __restrict__ sq) {
    constexpr int CPL = COUT / 64;          // cols per lane (1 or 2)
    int wv = threadIdx.x >> 6, lane = threadIdx.x & 63;
    int bn = blockIdx.x * 4 + wv;
    int b = bn >> 11;                       // NN = 2048
    int id = idx[(size_t)bn * KK + (lane < KK ? lane : 0)];
    float gv[CPL], sv[CPL], bv[CPL], mx[CPL];
#pragma unroll
    for (int q = 0; q < CPL; ++q) {
        int o = lane + 64 * q;
        gv[q] = G[(size_t)bn * COUT + o];
        sv[q] = scale[o];
        bv[q] = bias[o];
        mx[q] = -INFINITY;
    }
#pragma unroll
    for (int k = 0; k < KK; ++k) {
        int m = __shfl(id, k, 64);
        const float* hrow = H + (size_t)(b * NN + m) * COUT;
#pragma unroll
        for (int q = 0; q < CPL; ++q) {
            float v = hrow[lane + 64 * q] + gv[q];
            mx[q] = fmaxf(mx[q], lrelu(v * sv[q] + bv[q]));
        }
    }
    float* orow = X + (size_t)bn * XS + outoff;
    float v = 0.f;
#pragma unroll
    for (int q = 0; q < CPL; ++q) {
        orow[lane + 64 * q] = mx[q];
        v = fmaf(mx[q], mx[q], v);
    }
#pragma unroll
    for (int s = 1; s < 64; s <<= 1) v += __shfl_xor(v, s, 64);
    if (lane == 0) sq[bn] += v;
}

// ---- block5: g = lrelu((X . W5^T)*s5+b5), atomic max over n into gfeat -------------------
// R24 (kept): wave-uniform global X reads via readfirstlane (scalar pipe), LDS=0.
constexpr int RB = 32;
__global__ __launch_bounds__(512) void k_stage5(const float* __restrict__ X,
                                                const float* __restrict__ W5T,
                                                const float* __restrict__ s5,
                                                const float* __restrict__ b5,
                                                float* __restrict__ gfeat) {
    int blk = blockIdx.x;
    int b = blk / (NN / RB);
    int n0 = (blk % (NN / RB)) * RB;
    int tid = threadIdx.x;
    const float4* X4 = (const float4*)X;
    const float4* W5T4 = (const float4*)W5T;   // [XS][256] float4 per row
    int og = tid & 255;                   // output float4 slot (4 outputs)
    int r0 = __builtin_amdgcn_readfirstlane((tid >> 8) * 16);  // wave-uniform row group
    const float4* xrows = X4 + (size_t)(b * NN + n0 + r0) * X4S;
    float acc[16][4] = {};
    for (int c4 = 0; c4 < X4S; ++c4) {
        float4 w0 = W5T4[(size_t)(4 * c4 + 0) * 256 + og];
        float4 w1 = W5T4[(size_t)(4 * c4 + 1) * 256 + og];
        float4 w2 = W5T4[(size_t)(4 * c4 + 2) * 256 + og];
        float4 w3 = W5T4[(size_t)(4 * c4 + 3) * 256 + og];
#pragma unroll
        for (int r = 0; r < 16; ++r) {
            float4 a = xrows[(size_t)r * X4S + c4];   // uniform addr -> scalar load
            acc[r][0] = fmaf(a.x, w0.x, acc[r][0]);
            acc[r][1] = fmaf(a.x, w0.y, acc[r][1]);
            acc[r][2] = fmaf(a.x, w0.z, acc[r][2]);
            acc[r][3] = fmaf(a.x, w0.w, acc[r][3]);
            acc[r][0] = fmaf(a.y, w1.x, acc[r][0]);
            acc[r][1] = fmaf(a.y, w1.y, acc[r][1]);
            acc[r][2] = fmaf(a.y, w1.z, acc[r][2]);
            acc[r][3] = fmaf(a.y, w1.w, acc[r][3]);
            acc[r][0] = fmaf(a.z, w2.x, acc[r][0]);
            acc[r][1] = fmaf(a.z, w2.y, acc[r][1]);
            acc[r][2] = fmaf(a.z, w2.z, acc[r][2]);
            acc[r][3] = fmaf(a.z, w2.w, acc[r][3]);
            acc[r][0] = fmaf(a.w, w3.x, acc[r][0]);
            acc[r][1] = fmaf(a.w, w3.y, acc[r][1]);
            acc[r][2] = fmaf(a.w, w3.z, acc[r][2]);
            acc[r][3] = fmaf(a.w, w3.w, acc[r][3]);
        }
    }
    int o0 = og * 4;
#pragma unroll
    for (int i = 0; i < 4; ++i) {
        int o = o0 + i;
        float s = s5[o], bbv = b5[o];
        float mx = -INFINITY;
#pragma unroll
        for (int r = 0; r < 16; ++r) {
            float v = lrelu(acc[r][i] * s + bbv);
            mx = fmaxf(v, mx);
        }
        atomicMaxF(&gfeat[b * 1024 + o], mx);
    }
}

// ---- fused FC head: fc1 -> fc2 -> fc3 per batch row, intermediates in LDS ----------------
__global__ __launch_bounds__(256) void k_fc(const float* __restrict__ gfeat,
                                            const float* __restrict__ fW1, const float* __restrict__ fb1,
                                            const float* __restrict__ fs1, const float* __restrict__ fB1,
                                            const float* __restrict__ fW2, const float* __restrict__ fb2,
                                            const float* __restrict__ fs2, const float* __restrict__ fB2,
                                            const float* __restrict__ fW3, const float* __restrict__ fb3,
                                            float* __restrict__ logits) {
    int b = blockIdx.x;
    __shared__ float g[1024];
    __shared__ float h1s[512];
    __shared__ float h2s[256];
    int tid = threadIdx.x;
    for (int j = tid; j < 1024; j += 256) g[j] = gfeat[b * 1024 + j];
    __syncthreads();
    for (int o = tid; o < 512; o += 256) {
        const float* wr = fW1 + (size_t)o * 1024;
        float acc = 0.f;
        for (int c = 0; c < 1024; ++c) acc = fmaf(g[c], wr[c], acc);
        h1s[o] = lrelu((acc + fb1[o]) * fs1[o] + fB1[o]);
    }
    __syncthreads();
    {
        int o = tid;
        const float* wr = fW2 + (size_t)o * 512;
        float acc = 0.f;
        for (int c = 0; c < 512; ++c) acc = fmaf(h1s[c], wr[c], acc);
        h2s[o] = lrelu((acc + fb2[o]) * fs2[o] + fB2[o]);
    }
    __syncthreads();
    if (tid < 40) {
        const float* wr = fW3 + (size_t)tid * 256;
        float acc = 0.f;
        for (int c = 0; c < 256; ++c) acc = fmaf(h2s[c], wr[c], acc);
        logits[b * 40 + tid] = acc + fb3[tid];
    }
}

extern "C" void kernel_launch(void* const* d_in, const int* in_sizes, int n_in,
                              void* d_out, int out_size, void* d_ws, size_t ws_size,
                              hipStream_t stream) {
    const float* x   = (const float*)d_in[0];
    const float* W1  = (const float*)d_in[1];
    const float* s1  = (const float*)d_in[2];
    const float* b1  = (const float*)d_in[3];
    const float* W2  = (const float*)d_in[4];
    const float* s2  = (const float*)d_in[5];
    const float* b2  = (const float*)d_in[6];
    const float* W3  = (const float*)d_in[7];
    const float* s3  = (const float*)d_in[8];
    const float* b3  = (const float*)d_in[9];
    const float* W4  = (const float*)d_in[10];
    const float* s4  = (const float*)d_in[11];
    const float* b4  = (const float*)d_in[12];
    const float* W5  = (const float*)d_in[13];
    const float* s5  = (const float*)d_in[14];
    const float* b5  = (const float*)d_in[15];
    const float* fW1 = (const float*)d_in[16];
    const float* fb1 = (const float*)d_in[17];
    const float* fs1 = (const float*)d_in[18];
    const float* fB1 = (const float*)d_in[19];
    const float* fW2 = (const float*)d_in[20];
    const float* fb2 = (const float*)d_in[21];
    const float* fs2 = (const float*)d_in[22];
    const float* fB2 = (const float*)d_in[23];
    const float* fW3 = (const float*)d_in[24];
    const float* fb3 = (const float*)d_in[25];

    float* out    = (float*)d_out;
    float* logits = out;          // 8*40
    float* gfeat  = out + 320;    // 8*1024

    char* ws = (char*)d_ws;
    size_t off = 0;
    auto alloc = [&](size_t bytes) -> void* {
        void* p = ws + off;
        off += (bytes + 255) & ~(size_t)255;
        return p;
    };
    float* X    = (float*)alloc((size_t)BB * NN * XS * 4);      // 21.2 MB
    float* sq   = (float*)alloc((size_t)BB * NN * 4);
    float* dist = (float*)alloc((size_t)BB * NN * NN * 4);      // 134 MB
    int*   idx  = (int*)  alloc((size_t)BB * NN * KK * 4);
    float4* WT4 = (float4*)alloc((size_t)WTOT * 16);            // 305 KB
    float* H    = (float*)alloc((size_t)BB * NN * 128 * 4);     // 8.4 MB
    float* G    = (float*)alloc((size_t)BB * NN * 128 * 4);     // 8.4 MB
    float* W5T  = (float*)alloc((size_t)XS * 1024 * 4);
    (void)ws_size; (void)in_sizes; (void)n_in; (void)out_size;

    // one-shot prep: WT packs + W5T + gfeat init + transpose/sq0 + X zero-fill
    int prepTot = WTOT + XS * 1024 + BB * 1024 + BB * NN + BB * NN * 80;
    k_prep_all<<<(prepTot + 255) / 256, 256, 0, stream>>>(W1, W2, W3, W4, W5, x,
                                                          WT4, W5T, gfeat, X, sq);

    const int Cs[4]    = {3, 67, 131, 195};
    const int offs[4]  = {3, 67, 131, 195};
    const int WOFF[4]  = {0, 128, 2304, 6528};  // channel-row base in packed WT4
    const float* ss[4] = {s1, s2, s3, s4};
    const float* bs[4] = {b1, b2, b3, b4};

    constexpr int NT = NN / TM;                 // 16 tiles per dim
    constexpr int NBLK = NT * (NT + 1) / 2;     // 136 lower-triangle tiles
    for (int st = 0; st < 4; ++st) {
        int C = Cs[st];
        dim3 dg(NBLK, 1, BB);
        k_dist<<<dg, 256, 0, stream>>>(X, sq, dist, C);
        k_select<<<BB * NN, 64, 0, stream>>>(dist, idx);
        const float4* wt = WT4 + WOFF[st];
        switch (st) {
            case 0:
                k_hg<1, 64><<<BB * NN / 32, 256, 0, stream>>>(X, wt, H, G);
                k_edgemax<64><<<BB * NN / 4, 256, 0, stream>>>(H, G, idx, ss[st], bs[st], offs[st], X, sq);
                break;
            case 1:
                k_hg<17, 64><<<BB * NN / 32, 256, 0, stream>>>(X, wt, H, G);
                k_edgemax<64><<<BB * NN / 4, 256, 0, stream>>>(H, G, idx, ss[st], bs[st], offs[st], X, sq);
                break;
            case 2:
                k_hg<33, 64><<<BB * NN / 32, 256, 0, stream>>>(X, wt, H, G);
                k_edgemax<64><<<BB * NN / 4, 256, 0, stream>>>(H, G, idx, ss[st], bs[st], offs[st], X, sq);
                break;
            case 3:
                k_hg<49, 128><<<BB * NN / 32, 256, 0, stream>>>(X, wt, H, G);
                k_edgemax<128><<<BB * NN / 4, 256, 0, stream>>>(H, G, idx, ss[st], bs[st], offs[st], X, sq);
                break;
        }
    }

    k_stage5<<<BB * (NN / RB), 512, 0, stream>>>(X, W5T, s5, b5, gfeat);
    k_fc<<<BB, 256, 0, stream>>>(gfeat, fW1, fb1, fs1, fB1,
                                 fW2, fb2, fs2, fB2, fW3, fb3, logits);
}

// Round 20
// 990.621 us; speedup vs baseline: 1.0772x; 1.0772x over previous
//
#include <hip/hip_runtime.h>
#include <math.h>

// LDGCNN forward: 4 EdgeConv blocks (knn K=20) + 1x1 conv block + global max pool + 3 FC.
// B=8, N=2048. Feature buffer X: (B, N, XS) rows, columns [pts(3)|f1(64)|f2(64)|f3(64)|f4(128)].
// XS=324 keeps rows 16B-aligned for float4 loads (column 323 is an unused pad).
//
// Final form (R29 = revert to R18-measured best, 1011us; session start 1748us):
// R17: EdgeConv linearized: h[n,k,o] = H[idx[n,k],o] + G[n,o] -> dense GEMM (k_hg, 20x
//      fewer FLOPs, no gather) + cache-resident gather+max (k_edgemax).
// R19/R24: k_stage5 RB=32 + wave-uniform scalar X loads via readfirstlane (LDS=0).
// R23: k_dist float4 B-frags + direct float4 writes.
// R25: k_select exact radix-select (SET semantics — downstream max-pool is order-invariant).
// Rejected by measurement: software pipelining/dbuf (VGPR/occupancy collapse, R17/R26),
// 1:32-LDS stage5 variants (allocator, R20-R22), one-wave select (R28, neutral-negative).

constexpr int BB = 8;
constexpr int NN = 2048;
constexpr int KK = 20;
constexpr int CT = 323;
constexpr int XS = 324;
constexpr int X4S = XS / 4;   // 81 float4 per row
constexpr float NEGS = 0.2f;

__device__ __forceinline__ float lrelu(float v) { return v > 0.0f ? v : NEGS * v; }

__device__ __forceinline__ void atomicMaxF(float* addr, float v) {
    if (v >= 0.0f) atomicMax((int*)addr, __float_as_int(v));
    else           atomicMin((unsigned int*)addr, __float_as_uint(v));
}

__device__ __forceinline__ void fma4(float4& a, float x, const float4 w) {
    a.x = fmaf(x, w.x, a.x); a.y = fmaf(x, w.y, a.y);
    a.z = fmaf(x, w.z, a.z); a.w = fmaf(x, w.w, a.w);
}

// ---- fused prep: WT packs + W5T transpose + gfeat init + transpose/sq0 + X zero-fill -----
constexpr int WTOT = 19072;
__global__ void k_prep_all(const float* __restrict__ W1, const float* __restrict__ W2,
                           const float* __restrict__ W3, const float* __restrict__ W4,
                           const float* __restrict__ W5, const float* __restrict__ x,
                           float4* __restrict__ WT4, float* __restrict__ W5T,
                           float* __restrict__ gfeat, float* __restrict__ X,
                           float* __restrict__ sq) {
    int j = blockIdx.x * blockDim.x + threadIdx.x;
    if (j < WTOT) {
        int base, Cout, C;
        const float* W;
        if (j < 128)       { base = 0;    Cout = 64;  C = 3;   W = W1; }
        else if (j < 2304) { base = 128;  Cout = 64;  C = 67;  W = W2; }
        else if (j < 6528) { base = 2304; Cout = 64;  C = 131; W = W3; }
        else               { base = 6528; Cout = 128; C = 195; W = W4; }
        int W4w = Cout / 2;                 // 2*Cout/4 float4 groups per channel row
        int local = j - base;
        int c = local / W4w, og = local - c * W4w;
        float v[4];
#pragma unroll
        for (int q = 0; q < 4; ++q) {
            int o2 = 4 * og + q;
            if (c >= C) v[q] = 0.f;
            else if (o2 < Cout) v[q] = W[(size_t)o2 * 2 * C + c];
            else {
                int o = o2 - Cout;
                v[q] = W[(size_t)o * 2 * C + C + c] - W[(size_t)o * 2 * C + c];
            }
        }
        WT4[j] = make_float4(v[0], v[1], v[2], v[3]);
    } else if (j < WTOT + XS * 1024) {
        int t = j - WTOT;
        int c = t / 1024, o = t % 1024;
        W5T[t] = (c < CT) ? W5[(size_t)o * CT + c] : 0.f;   // row 323 zeroed
    } else if (j < WTOT + XS * 1024 + BB * 1024) {
        gfeat[j - WTOT - XS * 1024] = -INFINITY;
    } else if (j < WTOT + XS * 1024 + BB * 1024 + BB * NN) {
        int i = j - WTOT - XS * 1024 - BB * 1024;            // b*NN + n
        int b = i >> 11, n = i & 2047;
        const float* xb = x + (size_t)b * 3 * NN;
        float vx = xb[n], vy = xb[NN + n], vz = xb[2 * NN + n];
        float* row = X + (size_t)i * XS;
        row[0] = vx; row[1] = vy; row[2] = vz; row[3] = 0.f;
        sq[i] = vx * vx + vy * vy + vz * vz;
    } else if (j < WTOT + XS * 1024 + BB * 1024 + BB * NN + BB * NN * 80) {
        // zero-fill X feature columns (float4 indices 1..80 of each row; col 3 done above)
        int t = j - (WTOT + XS * 1024 + BB * 1024 + BB * NN);
        int row = t / 80, c4 = 1 + (t - 80 * row);
        ((float4*)X)[(size_t)row * X4S + c4] = make_float4(0.f, 0.f, 0.f, 0.f);
    }
}

// ---- dist[b][n][m] = max(sq_n + sq_m - 2*dot, 0) — SYMMETRIC: only tiles ti>=tj ----------
// 128x128 tile, 8x8 per thread. Thread owns cols {tx*4..+3, 64+tx*4..+3}; B fragment is
// 2 ds_read_b128. Off-diagonal: direct float4 writes + mirrored 4-pass LDS transpose.
constexpr int TM = 128;
__global__ __launch_bounds__(256) void k_dist(const float* __restrict__ X,
                                              const float* __restrict__ sq,
                                              float* __restrict__ dist, int C) {
    int b = blockIdx.z;
    int blk = blockIdx.x;                 // 0..135 -> (ti, tj), ti >= tj
    int ti = (int)((sqrtf(8.0f * blk + 1.0f) - 1.0f) * 0.5f);
    while ((ti + 1) * (ti + 2) / 2 <= blk) ++ti;
    while (ti * (ti + 1) / 2 > blk) --ti;
    int tj = blk - ti * (ti + 1) / 2;
    int m0 = ti * TM;                     // col tile
    int n0 = tj * TM;                     // row tile
    __shared__ float smem[4352];          // 17 KB: staging (16 KB) / transpose T[32][129]
    float* AsB = smem;                    // As[16][TM]
    float* BsB = smem + 2048;             // Bs[16][TM]
    int tid = threadIdx.x;
    int tx = tid & 15;        // cols: m0 + h*64 + tx*4 + jj  (j = 4h+jj)
    int ty = tid >> 4;        // rows: n0 + ty*8 + i
    float acc[8][8] = {};
    const float* Xb = X + (size_t)b * NN * XS;
    int sr = tid & 127;       // staging row
    int sc0 = (tid >> 7) * 8; // staging channel half (0 or 8)
    for (int c0 = 0; c0 < C; c0 += 16) {
        const float* arow = Xb + (size_t)(n0 + sr) * XS + c0 + sc0;
        const float* brow = Xb + (size_t)(m0 + sr) * XS + c0 + sc0;
        float4 a0 = *(const float4*)(arow);
        float4 a1 = *(const float4*)(arow + 4);
        float4 b0 = *(const float4*)(brow);
        float4 b1 = *(const float4*)(brow + 4);
        float av[8] = {a0.x, a0.y, a0.z, a0.w, a1.x, a1.y, a1.z, a1.w};
        float bv8[8] = {b0.x, b0.y, b0.z, b0.w, b1.x, b1.y, b1.z, b1.w};
#pragma unroll
        for (int i = 0; i < 8; ++i) {
            bool inr = (c0 + sc0 + i) < C;
            AsB[(sc0 + i) * TM + sr] = inr ? av[i] : 0.f;
            BsB[(sc0 + i) * TM + sr] = inr ? bv8[i] : 0.f;
        }
        __syncthreads();
#pragma unroll
        for (int cc = 0; cc < 16; ++cc) {
            float4 a0r = *(const float4*)&AsB[cc * TM + ty * 8];
            float4 a1r = *(const float4*)&AsB[cc * TM + ty * 8 + 4];
            float a[8] = {a0r.x, a0r.y, a0r.z, a0r.w, a1r.x, a1r.y, a1r.z, a1r.w};
            float4 b0r = *(const float4*)&BsB[cc * TM + tx * 4];
            float4 b1r = *(const float4*)&BsB[cc * TM + 64 + tx * 4];
            float bv[8] = {b0r.x, b0r.y, b0r.z, b0r.w, b1r.x, b1r.y, b1r.z, b1r.w};
#pragma unroll
            for (int i = 0; i < 8; ++i)
#pragma unroll
                for (int j = 0; j < 8; ++j)
                    acc[i][j] = fmaf(a[i], bv[j], acc[i][j]);
        }
        __syncthreads();
    }
    const float* sqb = sq + b * NN;
    float* db = dist + (size_t)b * NN * NN;
    float sm[8];
#pragma unroll
    for (int j = 0; j < 8; ++j) sm[j] = sqb[m0 + (j >> 2) * 64 + tx * 4 + (j & 3)];
#pragma unroll
    for (int i = 0; i < 8; ++i) {
        int n = n0 + ty * 8 + i;
        float sn = sqb[n];
#pragma unroll
        for (int j = 0; j < 8; ++j) {
            float d = fmaxf(sn + sm[j] - 2.f * acc[i][j], 0.f);
            acc[i][j] = d;                                   // keep for mirror
        }
        *(float4*)&db[(size_t)n * NN + m0 + tx * 4] =
            make_float4(acc[i][0], acc[i][1], acc[i][2], acc[i][3]);
        *(float4*)&db[(size_t)n * NN + m0 + 64 + tx * 4] =
            make_float4(acc[i][4], acc[i][5], acc[i][6], acc[i][7]);
    }
    if (ti != tj) {
        // mirrored tile: rows m0.., cols n0.. — 4 passes (h: col half, p2: 32-row group)
        float* T = smem;                  // [32][129]
        int r = tid >> 3;                 // 0..31
        int c0r = (tid & 7) * 16;         // 0..112
#pragma unroll
        for (int h = 0; h < 2; ++h) {
#pragma unroll
            for (int p2 = 0; p2 < 2; ++p2) {
                __syncthreads();          // protect staging/previous pass reads
                if ((tx >> 3) == p2) {    // tx in [8*p2, 8*p2+8): m_local in [32p2, 32p2+32)
#pragma unroll
                    for (int jj = 0; jj < 4; ++jj)
#pragma unroll
                        for (int i = 0; i < 8; ++i)
                            T[((tx & 7) * 4 + jj) * 129 + ty * 8 + i] = acc[i][h * 4 + jj];
                }
                __syncthreads();
                float v[16];
#pragma unroll
                for (int k = 0; k < 16; ++k) v[k] = T[r * 129 + c0r + k];
                float* dst = db + (size_t)(m0 + h * 64 + 32 * p2 + r) * NN + n0 + c0r;
#pragma unroll
                for (int k = 0; k < 4; ++k)
                    *(float4*)(dst + 4 * k) = make_float4(v[4 * k], v[4 * k + 1],
                                                          v[4 * k + 2], v[4 * k + 3]);
            }
        }
    }
}

// ---- top-K smallest per row (SET semantics — downstream is max-pool, order-invariant) ----
// key = (bits(d)<<11)|m (unique; ties -> lower m, matching lax.top_k). Radix-select the
// exact 20th-smallest key T, then emit all keys <= T (exactly 20, arbitrary order).
__global__ __launch_bounds__(128) void k_select(const float* __restrict__ dist,
                                                int* __restrict__ idx) {
    int bn = blockIdx.x;   // b*NN + n
    int tid = threadIdx.x;
    int wv = tid >> 6;
    int lane = tid & 63;
    const float* drow = dist + (size_t)bn * NN;
    int m0 = tid * 16;
    unsigned long long keys[16];
#pragma unroll
    for (int i = 0; i < 4; ++i) {
        float4 v = *(const float4*)(drow + m0 + 4 * i);
        keys[4 * i + 0] = ((unsigned long long)__float_as_uint(v.x) << 11) | (unsigned)(m0 + 4 * i + 0);
        keys[4 * i + 1] = ((unsigned long long)__float_as_uint(v.y) << 11) | (unsigned)(m0 + 4 * i + 1);
        keys[4 * i + 2] = ((unsigned long long)__float_as_uint(v.z) << 11) | (unsigned)(m0 + 4 * i + 2);
        keys[4 * i + 3] = ((unsigned long long)__float_as_uint(v.w) << 11) | (unsigned)(m0 + 4 * i + 3);
    }
    // Bound B: per-lane min16 -> wave max of minima -> min over waves. Each wave has 64
    // keys (its lane minima) <= its own bound, so >=64 keys <= B => T(20th) <= B.
    unsigned long long mn = keys[0];
#pragma unroll
    for (int i = 1; i < 16; ++i) mn = keys[i] < mn ? keys[i] : mn;
    unsigned long long mx = mn;
#pragma unroll
    for (int s = 1; s < 64; s <<= 1) {
        unsigned long long o = (unsigned long long)__shfl_xor((long long)mx, s, 64);
        mx = o > mx ? o : mx;
    }
    __shared__ unsigned long long sB[2];
    __shared__ unsigned long long sT;
    __shared__ int sWant;
    __shared__ int sCnt;
    __shared__ int hist[256];
    if (lane == 0) sB[wv] = mx;
    if (tid == 0) { sT = 0ull; sWant = KK; sCnt = 0; }
    __syncthreads();
    unsigned long long B = sB[0] < sB[1] ? sB[0] : sB[1];
    // 6-level byte-wise radix descent over the 43-bit key (levels cover bits [47:0]).
#pragma unroll 1
    for (int level = 0; level < 6; ++level) {
        int sh = 40 - 8 * level;
        hist[tid] = 0; hist[tid + 128] = 0;
        __syncthreads();
        unsigned long long pref = sT;
#pragma unroll
        for (int i = 0; i < 16; ++i) {
            unsigned long long k = keys[i];
            if (k <= B && (k >> (sh + 8)) == (pref >> (sh + 8)))
                atomicAdd(&hist[(int)((k >> sh) & 255)], 1);
        }
        __syncthreads();
        if (tid < 64) {
            int h0 = hist[4 * tid], h1 = hist[4 * tid + 1];
            int h2 = hist[4 * tid + 2], h3 = hist[4 * tid + 3];
            int s = h0 + h1 + h2 + h3;
            int inc = s;
#pragma unroll
            for (int d = 1; d < 64; d <<= 1) {
                int o = __shfl_up(inc, d, 64);
                if (lane >= d) inc += o;
            }
            int want = sWant;
            int c = inc - s;              // exclusive prefix
            int bsel = -1, rem = 0;
            if (c < want && want <= c + h0) { bsel = 4 * tid + 0; rem = want - c; } c += h0;
            if (bsel < 0 && c < want && want <= c + h1) { bsel = 4 * tid + 1; rem = want - c; } c += h1;
            if (bsel < 0 && c < want && want <= c + h2) { bsel = 4 * tid + 2; rem = want - c; } c += h2;
            if (bsel < 0 && c < want && want <= c + h3) { bsel = 4 * tid + 3; rem = want - c; }
            if (bsel >= 0) {
                sT = pref | ((unsigned long long)bsel << sh);
                sWant = rem;
            }
        }
        __syncthreads();
    }
    unsigned long long T = sT;            // exact 20th-smallest key
    int* orow = idx + (size_t)bn * KK;
#pragma unroll
    for (int i = 0; i < 16; ++i) {
        if (keys[i] <= T) {
            int s = atomicAdd(&sCnt, 1);
            orow[s] = (int)(keys[i] & 2047u);
        }
    }
}

// ---- k_hg: H = X.Wa^T, G = X.Wd^T — dense GEMM, no gather. -------------------------------
template <int KC4, int COUT>
__global__ __launch_bounds__(256)
void k_hg(const float* __restrict__ X, const float4* __restrict__ WT4,
          float* __restrict__ H, float* __restrict__ G) {
    constexpr int W4 = COUT / 2;            // 2*COUT/4 float4 outputs per channel row
    constexpr int RB2 = 32;
    constexpr int RPT = RB2 * W4 / 256;     // rows per thread (8 for COUT=128, 4 for 64)
    int bn0 = blockIdx.x * RB2;
    __shared__ float4 xs[RB2][KC4];
    int tid = threadIdx.x;
    const float4* X4 = (const float4*)X;
    for (int j = tid; j < RB2 * KC4; j += 256) {
        int r = j / KC4, c = j - r * KC4;
        xs[r][c] = X4[(size_t)(bn0 + r) * X4S + c];
    }
    __syncthreads();
    int og = tid & (W4 - 1);
    int rg = tid / W4;                      // row group
    float4 acc[RPT];
#pragma unroll
    for (int i = 0; i < RPT; ++i) acc[i] = make_float4(0.f, 0.f, 0.f, 0.f);
#pragma unroll 2
    for (int c4 = 0; c4 < KC4; ++c4) {
        float4 w0 = WT4[(size_t)(4 * c4 + 0) * W4 + og];
        float4 w1 = WT4[(size_t)(4 * c4 + 1) * W4 + og];
        float4 w2 = WT4[(size_t)(4 * c4 + 2) * W4 + og];
        float4 w3 = WT4[(size_t)(4 * c4 + 3) * W4 + og];
#pragma unroll
        for (int i = 0; i < RPT; ++i) {
            float4 xv = xs[rg * RPT + i][c4];
            fma4(acc[i], xv.x, w0);
            fma4(acc[i], xv.y, w1);
            fma4(acc[i], xv.z, w2);
            fma4(acc[i], xv.w, w3);
        }
    }
    int o2 = 4 * og;
#pragma unroll
    for (int i = 0; i < RPT; ++i) {
        int bn = bn0 + rg * RPT + i;
        if (o2 < COUT) *(float4*)&H[(size_t)bn * COUT + o2] = acc[i];
        else           *(float4*)&G[(size_t)bn * COUT + (o2 - COUT)] = acc[i];
    }
}

// ---- k_edgemax: X[bn, outoff+o] = max_k lrelu((H[idx[bn,k],o] + G[bn,o])*s+b) ------------
template <int COUT>
__global__ __launch_bounds__(256)
void k_edgemax(const float* __restrict__ H, const float* __restrict__ G,
               const int* __restrict__ idx, const float* __restrict__ scale,
               const float* __restrict__ bias, int outoff,
               float* __restrict__ X, float* __restrict__ sq) {
    constexpr int CPL = COUT / 64;          // cols per lane (1 or 2)
    int wv = threadIdx.x >> 6, lane = threadIdx.x & 63;
    int bn = blockIdx.x * 4 + wv;
    int b = bn >> 11;                       // NN = 2048
    int id = idx[(size_t)bn * KK + (lane < KK ? lane : 0)];
    float gv[CPL], sv[CPL], bv[CPL], mx[CPL];
#pragma unroll
    for (int q = 0; q < CPL; ++q) {
        int o = lane + 64 * q;
        gv[q] = G[(size_t)bn * COUT + o];
        sv[q] = scale[o];
        bv[q] = bias[o];
        mx[q] = -INFINITY;
    }
#pragma unroll
    for (int k = 0; k < KK; ++k) {
        int m = __shfl(id, k, 64);
        const float* hrow = H + (size_t)(b * NN + m) * COUT;
#pragma unroll
        for (int q = 0; q < CPL; ++q) {
            float v = hrow[lane + 64 * q] + gv[q];
            mx[q] = fmaxf(mx[q], lrelu(v * sv[q] + bv[q]));
        }
    }
    float* orow = X + (size_t)bn * XS + outoff;
    float v = 0.f;
#pragma unroll
    for (int q = 0; q < CPL; ++q) {
        orow[lane + 64 * q] = mx[q];
        v = fmaf(mx[q], mx[q], v);
    }
#pragma unroll
    for (int s = 1; s < 64; s <<= 1) v += __shfl_xor(v, s, 64);
    if (lane == 0) sq[bn] += v;
}

// ---- block5: g = lrelu((X . W5^T)*s5+b5), atomic max over n into gfeat -------------------
// R24 (kept): wave-uniform global X reads via readfirstlane (scalar pipe), LDS=0.
constexpr int RB = 32;
__global__ __launch_bounds__(512) void k_stage5(const float* __restrict__ X,
                                                const float* __restrict__ W5T,
                                                const float* __restrict__ s5,
                                                const float* __restrict__ b5,
                                                float* __restrict__ gfeat) {
    int blk = blockIdx.x;
    int b = blk / (NN / RB);
    int n0 = (blk % (NN / RB)) * RB;
    int tid = threadIdx.x;
    const float4* X4 = (const float4*)X;
    const float4* W5T4 = (const float4*)W5T;   // [XS][256] float4 per row
    int og = tid & 255;                   // output float4 slot (4 outputs)
    int r0 = __builtin_amdgcn_readfirstlane((tid >> 8) * 16);  // wave-uniform row group
    const float4* xrows = X4 + (size_t)(b * NN + n0 + r0) * X4S;
    float acc[16][4] = {};
    for (int c4 = 0; c4 < X4S; ++c4) {
        float4 w0 = W5T4[(size_t)(4 * c4 + 0) * 256 + og];
        float4 w1 = W5T4[(size_t)(4 * c4 + 1) * 256 + og];
        float4 w2 = W5T4[(size_t)(4 * c4 + 2) * 256 + og];
        float4 w3 = W5T4[(size_t)(4 * c4 + 3) * 256 + og];
#pragma unroll
        for (int r = 0; r < 16; ++r) {
            float4 a = xrows[(size_t)r * X4S + c4];   // uniform addr -> scalar load
            acc[r][0] = fmaf(a.x, w0.x, acc[r][0]);
            acc[r][1] = fmaf(a.x, w0.y, acc[r][1]);
            acc[r][2] = fmaf(a.x, w0.z, acc[r][2]);
            acc[r][3] = fmaf(a.x, w0.w, acc[r][3]);
            acc[r][0] = fmaf(a.y, w1.x, acc[r][0]);
            acc[r][1] = fmaf(a.y, w1.y, acc[r][1]);
            acc[r][2] = fmaf(a.y, w1.z, acc[r][2]);
            acc[r][3] = fmaf(a.y, w1.w, acc[r][3]);
            acc[r][0] = fmaf(a.z, w2.x, acc[r][0]);
            acc[r][1] = fmaf(a.z, w2.y, acc[r][1]);
            acc[r][2] = fmaf(a.z, w2.z, acc[r][2]);
            acc[r][3] = fmaf(a.z, w2.w, acc[r][3]);
            acc[r][0] = fmaf(a.w, w3.x, acc[r][0]);
            acc[r][1] = fmaf(a.w, w3.y, acc[r][1]);
            acc[r][2] = fmaf(a.w, w3.z, acc[r][2]);
            acc[r][3] = fmaf(a.w, w3.w, acc[r][3]);
        }
    }
    int o0 = og * 4;
#pragma unroll
    for (int i = 0; i < 4; ++i) {
        int o = o0 + i;
        float s = s5[o], bbv = b5[o];
        float mx = -INFINITY;
#pragma unroll
        for (int r = 0; r < 16; ++r) {
            float v = lrelu(acc[r][i] * s + bbv);
            mx = fmaxf(v, mx);
        }
        atomicMaxF(&gfeat[b * 1024 + o], mx);
    }
}

// ---- fused FC head: fc1 -> fc2 -> fc3 per batch row, intermediates in LDS ----------------
__global__ __launch_bounds__(256) void k_fc(const float* __restrict__ gfeat,
                                            const float* __restrict__ fW1, const float* __restrict__ fb1,
                                            const float* __restrict__ fs1, const float* __restrict__ fB1,
                                            const float* __restrict__ fW2, const float* __restrict__ fb2,
                                            const float* __restrict__ fs2, const float* __restrict__ fB2,
                                            const float* __restrict__ fW3, const float* __restrict__ fb3,
                                            float* __restrict__ logits) {
    int b = blockIdx.x;
    __shared__ float g[1024];
    __shared__ float h1s[512];
    __shared__ float h2s[256];
    int tid = threadIdx.x;
    for (int j = tid; j < 1024; j += 256) g[j] = gfeat[b * 1024 + j];
    __syncthreads();
    for (int o = tid; o < 512; o += 256) {
        const float* wr = fW1 + (size_t)o * 1024;
        float acc = 0.f;
        for (int c = 0; c < 1024; ++c) acc = fmaf(g[c], wr[c], acc);
        h1s[o] = lrelu((acc + fb1[o]) * fs1[o] + fB1[o]);
    }
    __syncthreads();
    {
        int o = tid;
        const float* wr = fW2 + (size_t)o * 512;
        float acc = 0.f;
        for (int c = 0; c < 512; ++c) acc = fmaf(h1s[c], wr[c], acc);
        h2s[o] = lrelu((acc + fb2[o]) * fs2[o] + fB2[o]);
    }
    __syncthreads();
    if (tid < 40) {
        const float* wr = fW3 + (size_t)tid * 256;
        float acc = 0.f;
        for (int c = 0; c < 256; ++c) acc = fmaf(h2s[c], wr[c], acc);
        logits[b * 40 + tid] = acc + fb3[tid];
    }
}

extern "C" void kernel_launch(void* const* d_in, const int* in_sizes, int n_in,
                              void* d_out, int out_size, void* d_ws, size_t ws_size,
                              hipStream_t stream) {
    const float* x   = (const float*)d_in[0];
    const float* W1  = (const float*)d_in[1];
    const float* s1  = (const float*)d_in[2];
    const float* b1  = (const float*)d_in[3];
    const float* W2  = (const float*)d_in[4];
    const float* s2  = (const float*)d_in[5];
    const float* b2  = (const float*)d_in[6];
    const float* W3  = (const float*)d_in[7];
    const float* s3  = (const float*)d_in[8];
    const float* b3  = (const float*)d_in[9];
    const float* W4  = (const float*)d_in[10];
    const float* s4  = (const float*)d_in[11];
    const float* b4  = (const float*)d_in[12];
    const float* W5  = (const float*)d_in[13];
    const float* s5  = (const float*)d_in[14];
    const float* b5  = (const float*)d_in[15];
    const float* fW1 = (const float*)d_in[16];
    const float* fb1 = (const float*)d_in[17];
    const float* fs1 = (const float*)d_in[18];
    const float* fB1 = (const float*)d_in[19];
    const float* fW2 = (const float*)d_in[20];
    const float* fb2 = (const float*)d_in[21];
    const float* fs2 = (const float*)d_in[22];
    const float* fB2 = (const float*)d_in[23];
    const float* fW3 = (const float*)d_in[24];
    const float* fb3 = (const float*)d_in[25];

    float* out    = (float*)d_out;
    float* logits = out;          // 8*40
    float* gfeat  = out + 320;    // 8*1024

    char* ws = (char*)d_ws;
    size_t off = 0;
    auto alloc = [&](size_t bytes) -> void* {
        void* p = ws + off;
        off += (bytes + 255) & ~(size_t)255;
        return p;
    };
    float* X    = (float*)alloc((size_t)BB * NN * XS * 4);      // 21.2 MB
    float* sq   = (float*)alloc((size_t)BB * NN * 4);
    float* dist = (float*)alloc((size_t)BB * NN * NN * 4);      // 134 MB
    int*   idx  = (int*)  alloc((size_t)BB * NN * KK * 4);
    float4* WT4 = (float4*)alloc((size_t)WTOT * 16);            // 305 KB
    float* H    = (float*)alloc((size_t)BB * NN * 128 * 4);     // 8.4 MB
    float* G    = (float*)alloc((size_t)BB * NN * 128 * 4);     // 8.4 MB
    float* W5T  = (float*)alloc((size_t)XS * 1024 * 4);
    (void)ws_size; (void)in_sizes; (void)n_in; (void)out_size;

    // one-shot prep: WT packs + W5T + gfeat init + transpose/sq0 + X zero-fill
    int prepTot = WTOT + XS * 1024 + BB * 1024 + BB * NN + BB * NN * 80;
    k_prep_all<<<(prepTot + 255) / 256, 256, 0, stream>>>(W1, W2, W3, W4, W5, x,
                                                          WT4, W5T, gfeat, X, sq);

    const int Cs[4]    = {3, 67, 131, 195};
    const int offs[4]  = {3, 67, 131, 195};
    const int WOFF[4]  = {0, 128, 2304, 6528};  // channel-row base in packed WT4
    const float* ss[4] = {s1, s2, s3, s4};
    const float* bs[4] = {b1, b2, b3, b4};

    constexpr int NT = NN / TM;                 // 16 tiles per dim
    constexpr int NBLK = NT * (NT + 1) / 2;     // 136 lower-triangle tiles
    for (int st = 0; st < 4; ++st) {
        int C = Cs[st];
        dim3 dg(NBLK, 1, BB);
        k_dist<<<dg, 256, 0, stream>>>(X, sq, dist, C);
        k_select<<<BB * NN, 128, 0, stream>>>(dist, idx);
        const float4* wt = WT4 + WOFF[st];
        switch (st) {
            case 0:
                k_hg<1, 64><<<BB * NN / 32, 256, 0, stream>>>(X, wt, H, G);
                k_edgemax<64><<<BB * NN / 4, 256, 0, stream>>>(H, G, idx, ss[st], bs[st], offs[st], X, sq);
                break;
            case 1:
                k_hg<17, 64><<<BB * NN / 32, 256, 0, stream>>>(X, wt, H, G);
                k_edgemax<64><<<BB * NN / 4, 256, 0, stream>>>(H, G, idx, ss[st], bs[st], offs[st], X, sq);
                break;
            case 2:
                k_hg<33, 64><<<BB * NN / 32, 256, 0, stream>>>(X, wt, H, G);
                k_edgemax<64><<<BB * NN / 4, 256, 0, stream>>>(H, G, idx, ss[st], bs[st], offs[st], X, sq);
                break;
            case 3:
                k_hg<49, 128><<<BB * NN / 32, 256, 0, stream>>>(X, wt, H, G);
                k_edgemax<128><<<BB * NN / 4, 256, 0, stream>>>(H, G, idx, ss[st], bs[st], offs[st], X, sq);
                break;
        }
    }

    k_stage5<<<BB * (NN / RB), 512, 0, stream>>>(X, W5T, s5, b5, gfeat);
    k_fc<<<BB, 256, 0, stream>>>(gfeat, fW1, fb1, fs1, fB1,
                                 fW2, fb2, fs2, fB2, fW3, fb3, logits);
}